// Round 5
// baseline (51.841 us; speedup 1.0000x reference)
//
#include <hip/hip_runtime.h>

// IAF spiking layer: data (B*T, F) fp32, B=32, T=1024, F=1024.
// One thread per (b,f) chain; t strictly sequential; 512 waves (2/CU).
//
// R4 insight: vmcnt is 6 bits -> HARD CAP 63 outstanding VMEM ops/wave.
//   R1 peaked at 60 (best, 44.6us); R2 hit 76 and R3 hit 72 -> both stalled
//   AT ISSUE (wave blocks mid-issue before computing ready data) -> regressed.
// Depth-in-bytes must come from WIDER ops, not more slots:
//   DEPTH=32 chunk = 8x global_load_lds(16B/lane) + 8x global_store_dwordx4
//   (via LDS transpose tile) = 16 slots/chunk -> P=4 prefetch,
//   max in-flight = 40 + 8 + 8 = 56 <= 63. 32 KB/wave reads in flight.
//
// vmcnt schedule (issue-first: wait, L(c+4), C(c)+S(c); order pinned by
// sched_barrier + asm memory clobbers):
//   head 24/32/40/40, steady 40, tail 40/40/32/24.

constexpr int T = 1024;
constexpr int F = 1024;
constexpr int DEPTH = 32;                  // t-steps per chunk
constexpr int CH = DEPTH * 64;             // 2048 floats = 8 KB per buffer
constexpr int RING = 5;                    // input ring buffers (P=4 -> 5)

#define WAITVM(N) asm volatile("s_waitcnt vmcnt(" #N ")" ::: "memory")
#define LGKM0()   asm volatile("s_waitcnt lgkmcnt(0)" ::: "memory")
#define SFENCE()  __builtin_amdgcn_sched_barrier(0)

__global__ __launch_bounds__(64) void iaf_kernel(const float* __restrict__ x,
                                                 float* __restrict__ out) {
    __shared__ float ring[RING * CH];      // 40 KB input ring
    __shared__ float outT[2 * CH];         // 16 KB output transpose (dbuf)

    const int lane = threadIdx.x;          // 0..63
    const int b = blockIdx.x >> 4;         // 32 batch rows
    const int f0 = (blockIdx.x & 15) * 64; // feature block base

    const size_t base = ((size_t)b * T) * F + f0;
    const float* __restrict__ p = x + base;      // row t at p + t*F
    float* __restrict__ qo = out + base;

    // global_load_lds lane map (verified R1-R3, absmax 0): instr r covers
    // global row k*32 + r*4 + (lane>>4), floats f0 + (lane&15)*4 .. +3;
    // LDS dest linear == row-major [32][64] float tile.
    const int lrow = lane >> 4;            // 0..3
    const int lcol = (lane & 15) * 4;      // float col within 64-wide block

    float s = 0.0f, a = 0.0f;

    auto issue = [&](int k, int rb) {      // 8x 16B global_load_lds = 8 slots
        float* lb = &ring[rb * CH];
#pragma unroll
        for (int r = 0; r < 8; ++r) {
            const float* g = p + (size_t)(k * DEPTH + r * 4 + lrow) * F + lcol;
            __builtin_amdgcn_global_load_lds(
                (const __attribute__((address_space(1))) void*)g,
                (__attribute__((address_space(3))) void*)(lb + r * 256),
                16, 0, 0);
        }
        SFENCE();
    };

    auto compute = [&](int k, int rb) {
        const float* lb = &ring[rb * CH];
        float* ot = &outT[(k & 1) * CH];
        // batched xv preload (R1-style): 32 ds_read_b32, banks lane%32
        // (2-way, free), independent of the recurrence -> pipelined.
        float xv[DEPTH];
#pragma unroll
        for (int i = 0; i < DEPTH; ++i) xv[i] = lb[i * 64 + lane];
#pragma unroll
        for (int i = 0; i < DEPTH; ++i) {
            // exact reference op order (bit-exact floor/relu feedback):
            s = (xv[i] + s) - a;
            s = fmaxf(s + 1.0f, 0.0f) - 1.0f;    // relu(s - (-1)) + (-1)
            a = floorf(fmaxf(s, 0.0f));          // == (s>0)?floor(s):0
            ot[i * 64 + lane] = a;               // ds_write, off-chain
        }
        LGKM0();     // drains the 32 ds_writes (issued over ~700cy: cheap)
        SFENCE();
        // transposed read + wide store: instr j covers t-rows 4j..4j+3;
        // lane -> row 4j+lrow, floats lcol..lcol+3 (16B aligned).
        // 8x ds_read_b128 (R3 proved conflict-free) + 8x store_dwordx4.
#pragma unroll
        for (int j = 0; j < 8; ++j) {
            const int row = j * 4 + lrow;
            const float4 v = *(const float4*)&ot[row * 64 + lcol];
            *(float4*)(qo + (size_t)(k * DEPTH + row) * F + lcol) = v;
        }
        SFENCE();
    };

    // prologue: 4 chunks in flight (32 slots)
    issue(0, 0); issue(1, 1); issue(2, 2); issue(3, 3);

    // head peels (ops outstanding after L(c)'s last load: 24/32/48/48;
    // waits are exact-or-tighter, and keep in-flight <= 56)
    WAITVM(24); issue(4, 4); compute(0, 0);
    WAITVM(32); issue(5, 0); compute(1, 1);
    WAITVM(40); issue(6, 1); compute(2, 2);
    WAITVM(40); issue(7, 2); compute(3, 3);

    // steady: exact bound 48 (3x8 loads + 3x8 stores after L(c)); use 40
    // for slot headroom -> max in-flight 40+8+8 = 56 <= 63, never stalls
    // at issue. chunk k lives in ring buffer k%5.
    int bc = 4, bl = 3;                    // c=4: compute 4%5=4, issue 8%5=3
    for (int c = 4; c <= 27; ++c) {
        WAITVM(40);
        issue(c + 4, bl);
        compute(c, bc);
        bc = (bc == RING - 1) ? 0 : bc + 1;
        bl = (bl == RING - 1) ? 0 : bl + 1;
    }

    // tail (chunks 28..31 -> buffers 3,4,0,1), exact-or-tighter waits
    WAITVM(40); compute(28, 3);
    WAITVM(40); compute(29, 4);
    WAITVM(32); compute(30, 0);
    WAITVM(24); compute(31, 1);
}

extern "C" void kernel_launch(void* const* d_in, const int* in_sizes, int n_in,
                              void* d_out, int out_size, void* d_ws, size_t ws_size,
                              hipStream_t stream) {
    const float* x = (const float*)d_in[0];
    float* out = (float*)d_out;
    // 512 blocks x 64 threads = 32768 chains; LDS 56 KB -> 2 blocks/CU.
    iaf_kernel<<<dim3(512), dim3(64), 0, stream>>>(x, out);
}

// Round 6
// 46.693 us; speedup vs baseline: 1.1103x; 1.1103x over previous
//
#include <hip/hip_runtime.h>

// IAF spiking layer: data (B*T, F) fp32, B=32, T=1024, F=1024.
// R5: producer/consumer wave specialization.
//   wave0 (compute): 64 chains, ds_read + recurrence + scalar stores.
//     ZERO vmcnt waits -> serial chain never couples to memory stalls.
//   wave1 (mover): pure global_load_lds pipeline, 7 chunks (56 KB) ahead,
//     counted vmcnt (never 0 in steady state), raw s_barrier handoff
//     (NOT __syncthreads - that drains vmcnt(0) and kills the pipeline).
//   512 blocks x 128 thr = 4 waves/CU (2 compute + 2 mover), all SIMDs busy.
//
// Lessons encoded: R3/R4 transpose-for-wide-stores = pure overhead on the
// compute wave (scalar 256B/inst stores are fully coalesced; same HBM bytes);
// R2 nt-stores = no FETCH change; R1's 44.6us = single-wave coupling.
//
// Barrier protocol (both waves execute exactly 32 s_barriers):
//   mover: issue L(0..6); WAITVM(48) [L0 landed]; BAR#0;
//          c=0..24: issue L(c+7); WAITVM(48) [L(c+1) landed]; BAR#(c+1)
//          tail waits 40/32/24/16/8/0 for bars #26..#31.
//   compute: c=0..31: BAR#c; consume ring[c&7]; recurrence; stores.
//   Ring slot (c+7)&7 == (c-1)&7 was consumed before BAR#c -> no overwrite
//   hazard. Max mover in-flight = 56 loads (only loads count: <= 63).

constexpr int T = 1024;
constexpr int F = 1024;
constexpr int DEPTH = 32;               // t-steps per chunk
constexpr int NC = T / DEPTH;           // 32 chunks
constexpr int CH = DEPTH * 64;          // 2048 floats = 8 KB per buffer
constexpr int RING = 8;                 // 64 KB ring -> 2 blocks/CU

#define WAITVM(N) asm volatile("s_waitcnt vmcnt(" #N ")" ::: "memory")
#define SFENCE()  __builtin_amdgcn_sched_barrier(0)
#define BAR()     do { SFENCE(); __builtin_amdgcn_s_barrier(); SFENCE(); } while (0)

__global__ __launch_bounds__(128) void iaf_kernel(const float* __restrict__ x,
                                                  float* __restrict__ out) {
    __shared__ float ring[RING * CH];   // 64 KB

    const int lane = threadIdx.x & 63;
    const int wave = threadIdx.x >> 6;  // 0 = compute, 1 = mover
    const int b = blockIdx.x >> 4;      // 32 batch rows
    const int f0 = (blockIdx.x & 15) * 64;
    const size_t base = ((size_t)b * T) * F + f0;

    if (wave == 1) {
        // ---------------- mover: pure load pipeline ----------------
        const float* __restrict__ p = x + base;
        // global_load_lds lane map (verified R1-R4, absmax 0): instr r of
        // chunk k covers global row k*32 + r*4 + (lane>>4), floats
        // f0 + (lane&15)*4 .. +3; LDS dest linear == row-major [32][64].
        const int lrow = lane >> 4;
        const int lcol = (lane & 15) * 4;

        auto issue = [&](int k) {       // 8x 16B global_load_lds = 8 slots
            float* lb = &ring[(k & 7) * CH];
#pragma unroll
            for (int r = 0; r < 8; ++r) {
                const float* g = p + (size_t)(k * DEPTH + r * 4 + lrow) * F + lcol;
                __builtin_amdgcn_global_load_lds(
                    (const __attribute__((address_space(1))) void*)g,
                    (__attribute__((address_space(3))) void*)(lb + r * 256),
                    16, 0, 0);
            }
            SFENCE();
        };

        issue(0); issue(1); issue(2); issue(3); issue(4); issue(5); issue(6);
        WAITVM(48);              // L(0) landed (48 = 6x8 issued after it)
        BAR();                   // bar #0
        for (int c = 0; c <= 24; ++c) {
            issue(c + 7);        // into slot (c-1)&7, consumed before bar #c
            WAITVM(48);          // L(c+1) landed: L(c+2..c+7) = 48 after it
            BAR();               // bar #(c+1)
        }
        // tail: exact counts for L(26..31)
        WAITVM(40); BAR();       // #26
        WAITVM(32); BAR();       // #27
        WAITVM(24); BAR();       // #28
        WAITVM(16); BAR();       // #29
        WAITVM(8);  BAR();       // #30
        WAITVM(0);  BAR();       // #31
    } else {
        // ---------------- compute: zero vmem-wait recurrence ----------------
        float* __restrict__ q = out + base + lane;
        float s = 0.0f, a = 0.0f;
        for (int c = 0; c < NC; ++c) {
            BAR();               // chunk c guaranteed landed by mover
            const float* lb = &ring[(c & 7) * CH];
            float xv[DEPTH];     // batched preload: banks lane%32, 2-way free
#pragma unroll
            for (int i = 0; i < DEPTH; ++i) xv[i] = lb[i * 64 + lane];
#pragma unroll
            for (int i = 0; i < DEPTH; ++i) {
                // bit-exact reference semantics, shortened dep chain:
                // s1 = (x + s) - a
                // t2 = s1 + 1; s = max(t2,0) - 1     (relu clamp, exact order)
                // a = floor(max(t2,1) - 1) == floor(max(s,0)) == (s>0?floor(s):0)
                //   (t2>=1: both t2-1; t2<1: both 0 -> identical values)
                const float s1 = (xv[i] + s) - a;
                const float t2 = s1 + 1.0f;
                s = fmaxf(t2, 0.0f) - 1.0f;
                a = floorf(fmaxf(t2, 1.0f) - 1.0f);
                q[(size_t)(c * DEPTH + i) * F] = a;   // coalesced 256B/inst
            }
            SFENCE();
        }
    }
}

extern "C" void kernel_launch(void* const* d_in, const int* in_sizes, int n_in,
                              void* d_out, int out_size, void* d_ws, size_t ws_size,
                              hipStream_t stream) {
    const float* x = (const float*)d_in[0];
    float* out = (float*)d_out;
    // 512 blocks x 128 threads: wave0 computes 64 chains, wave1 moves data.
    // LDS 64 KB -> 2 blocks/CU -> 4 waves/CU (all 4 SIMDs busy).
    iaf_kernel<<<dim3(512), dim3(128), 0, stream>>>(x, out);
}